// Round 1
// 73.597 us; speedup vs baseline: 1.0200x; 1.0200x over previous
//
#include <hip/hip_runtime.h>

#define BATCH   8
#define SHAPE_N 8192
#define SKEL_M  2048
#define CHUNK   512    // b-points per LDS chunk: 512 * 32 B = 16 KB (double-buffered)

// ws layout (floats):
//   [0, 512):            dir1 per-block partial sums (plain stores)
//   [512, 66048):        dir2 partial mins, [quarter q<4][batch b<8][apt 2048]
//   [66048, 197120):     skel converted  (8 batches * 4096 uint4 = 512 KB)
//   [197120, 721408):    shape converted (8 batches * 16384 uint4 = 2 MB)
// Every result slot read by cd_reduce is written by cd_main in the same
// iteration; converted arrays are written by cd_prep in the same iteration.
// No ws init dependence, no atomics (re-poison-safe).
#define WS2_OFF 512
#define SKC_OFF 66048
#define SHC_OFF (66048 + 131072)

// MFMA frag types (gfx950: 32x32x16 bf16 — A/B = 8 bf16 (4 VGPRs), C/D = 16 f32)
typedef short bf16x8 __attribute__((ext_vector_type(8)));
typedef float f32x16 __attribute__((ext_vector_type(16)));
union FragU { bf16x8 v; uint4 u4; };

// round-to-nearest-even f32 -> bf16 (result in low 16 bits)
__device__ __forceinline__ unsigned int f2bf(float a) {
    unsigned int u = __float_as_uint(a);
    return (u + 0x7FFFu + ((u >> 16) & 1u)) >> 16;
}
__device__ __forceinline__ float bf2f(unsigned int h) {
    return __uint_as_float(h << 16);
}
__device__ __forceinline__ unsigned int pack2(unsigned int lo, unsigned int hi) {
    return lo | (hi << 16);
}
// v ~= hi + lo (two bf16), residual ~2^-16 relative
__device__ __forceinline__ void bfsplit(float v, unsigned int& h, unsigned int& l) {
    h = f2bf(v);
    l = f2bf(v - bf2f(h));
}

// Converted A-operand (streamed side) for one b-point, hi/lo scheme identical
// to the verified R7/R8 kernels:
//   k=0..2 c_hi  k=3 rb_hi  k=4..6 c_hi  k=7 rb_lo | k=8..10 c_lo  k=11..15 0
__device__ __forceinline__ void conv_point(float bx, float by, float bz,
                                           uint4& hi, uint4& lo) {
    const float cx = -2.f * bx, cy = -2.f * by, cz = -2.f * bz;
    const float rb = bx * bx + by * by + bz * bz;
    unsigned int chx, clx, chy, cly, chz, clz, rbh, rbl;
    bfsplit(cx, chx, clx); bfsplit(cy, chy, cly); bfsplit(cz, chz, clz);
    bfsplit(rb, rbh, rbl);
    hi = make_uint4(pack2(chx, chy), pack2(chz, rbh),
                    pack2(chx, chy), pack2(chz, rbl));
    lo = make_uint4(pack2(clx, cly), pack2(clz, 0u), 0u, 0u);
}

// async global->LDS, 16 B per lane (global_load_lds_dwordx4)
__device__ __forceinline__ void gl16(const char* g, char* l) {
    __builtin_amdgcn_global_load_lds(
        (const __attribute__((address_space(1))) void*)g,
        (__attribute__((address_space(3))) void*)l, 16, 0, 0);
}

// ---------------------------------------------------------------------------
// cd_prep: convert every b-side point ONCE into the exact LDS fragment order
// (group g of 32 points: 32 hi-uint4 then 32 lo-uint4 = 1 KB/group), so
// cd_main can stage with linear global_load_lds (no VALU, no layout fixup).
// 81920 points total -> grid 320 x 256, one point per thread.
// ---------------------------------------------------------------------------
__global__ __launch_bounds__(256) void cd_prep(
    const float* __restrict__ shape, const float* __restrict__ skel,
    float* __restrict__ ws)
{
    const int p = blockIdx.x * 256 + threadIdx.x;      // 0 .. 81919
    const float* q;
    uint4* dst;
    int idx;
    if (p < BATCH * SKEL_M) {                          // skel: stride 3
        const int b = p >> 11; idx = p & (SKEL_M - 1);
        q = skel + (size_t)p * 3;
        dst = (uint4*)(ws + SKC_OFF) + (size_t)b * 4096;
    } else {                                           // shape: stride 6
        const int s = p - BATCH * SKEL_M;
        const int b = s >> 13; idx = s & (SHAPE_N - 1);
        q = shape + (size_t)s * 6;
        dst = (uint4*)(ws + SHC_OFF) + (size_t)b * 16384;
    }
    uint4 hi, lo;
    conv_point(q[0], q[1], q[2], hi, lo);
    const int g = idx >> 5, r = idx & 31;
    dst[g * 64 + r]      = hi;
    dst[g * 64 + 32 + r] = lo;
}

// ---------------------------------------------------------------------------
// Scan 2048 converted b-points against the block's 128 resident a-points.
// Each wave holds ALL 4 a-group B-fragments and scans 1/4 of the b-groups:
// one ds_read_b128 feeds 4 MFMAs (LDS read traffic /4 vs one-group-per-wave).
// Staging: double-buffered 16 KB chunks via global_load_lds, prefetch issued
// before the MFMA phase so load latency hides under compute.
// ---------------------------------------------------------------------------
template <int SA>
__device__ __forceinline__ void cd_scan2(
    const float* __restrict__ Araw,   // 128 a-points, stride SA
    const uint4* __restrict__ Bconv,  // 4096 uint4 = 2048 converted b-points
    uint4* __restrict__ sB,           // LDS: 2048 uint4 = 2 x 16 KB buffers
    float* rmin, float* ra)           // [4] outputs per lane (a-group j)
{
    const int tid = threadIdx.x;
    const int l = tid & 63, wv = tid >> 6;
    const unsigned int one = 0x3F80u;

    // resident B-operand frags: col n = l&31; lane-halves are k 0..7 / 8..15
    FragU bf[4];
#pragma unroll
    for (int j = 0; j < 4; ++j) {
        const float* p = Araw + (size_t)(j * 32 + (l & 31)) * SA;
        const float x = p[0], y = p[1], z = p[2];
        ra[j] = x * x + y * y + z * z;
        unsigned int hx, lx, hy, ly, hz, lz;
        bfsplit(x, hx, lx); bfsplit(y, hy, ly); bfsplit(z, hz, lz);
        if (l < 32)    // k=0..7: (a_hi, 1, a_lo, 1)
            bf[j].u4 = make_uint4(pack2(hx, hy), pack2(hz, one),
                                  pack2(lx, ly), pack2(lz, one));
        else           // k=8..15: (a_hi, 0, 0, 0)
            bf[j].u4 = make_uint4(pack2(hx, hy), pack2(hz, 0u), 0u, 0u);
        rmin[j] = 3.4e38f;
    }

    const f32x16 Z = {0,0,0,0,0,0,0,0,0,0,0,0,0,0,0,0};
    const char* gbase = (const char*)Bconv;
    char* lbase = (char*)sB;

    // prologue: stage chunk 0 -> buffer 0 (4 x 16 B per thread = 16 KB)
#pragma unroll
    for (int k = 0; k < 4; ++k)
        gl16(gbase + k * 4096 + tid * 16, lbase + k * 4096 + tid * 16);
    __syncthreads();   // compiler drains vmcnt before s_barrier

    for (int c = 0; c < 4; ++c) {
        // prefetch chunk c+1 into the other buffer; stays in flight during
        // the MFMA phase, drained by the end-of-iteration barrier.
        if (c < 3) {
            const char* src = gbase + (c + 1) * 16384;
            char* dstl = lbase + (((c + 1) & 1) ? 16384 : 0);
#pragma unroll
            for (int k = 0; k < 4; ++k)
                gl16(src + k * 4096 + tid * 16, dstl + k * 4096 + tid * 16);
        }
        // this wave's 4 b-groups of the chunk: one frag read -> 4 MFMAs
        unsigned int o = (unsigned int)(((c & 1) ? 16384 : 0) + wv * 4096 +
                                        (l >> 5) * 512 + (l & 31) * 16);
#pragma unroll
        for (int g = 0; g < 4; ++g) {
            FragU af;
            af.u4 = *(const uint4*)(lbase + o);
            o += 1024;
#pragma unroll
            for (int j = 0; j < 4; ++j) {
                f32x16 D = __builtin_amdgcn_mfma_f32_32x32x16_bf16(
                    af.v, bf[j].v, Z, 0, 0, 0);
                // 8x v_min3 tree + 1 min3 into the running min
                const float t0 = fminf(fminf(D[0],  D[1]),  D[2]);
                const float t1 = fminf(fminf(D[3],  D[4]),  D[5]);
                const float t2 = fminf(fminf(D[6],  D[7]),  D[8]);
                const float t3 = fminf(fminf(D[9],  D[10]), D[11]);
                const float t4 = fminf(fminf(D[12], D[13]), D[14]);
                const float u0 = fminf(fminf(t0, t1), t2);
                const float u1 = fminf(fminf(t3, t4), D[15]);
                rmin[j] = fminf(rmin[j], fminf(u0, u1));
            }
        }
        __syncthreads();
    }
    // lane l and l^32 cover complementary rows (b-points) of the same col
#pragma unroll
    for (int j = 0; j < 4; ++j)
        rmin[j] = fminf(rmin[j], __shfl_xor(rmin[j], 32, 64));
}

// ---------------------------------------------------------------------------
// 1024 equal blocks (64 MFMA steps/wave), 4 blocks/CU (~35 KB LDS each):
//   [0,512):    dir1 — a = shape (128 pts), b = full skel (converted).
//               Cross-wave min -> sqrt+block-sum -> ws[bid].
//   [512,1024): dir2 — a = skel (128 pts), b = one converted shape quarter.
//               Cross-wave min -> plain stores into this quarter's ws slice.
// ---------------------------------------------------------------------------
__global__ __launch_bounds__(256, 4) void cd_main(
    const float* __restrict__ shape, const float* __restrict__ skel,
    float* __restrict__ ws)
{
    __shared__ uint4 sB[CHUNK * 4];    // 32 KB: 2 buffers x 16 KB
    __shared__ float smin[4][128];
    __shared__ float sra[128];
    __shared__ float s_wsum[2];
    const int tid = threadIdx.x;
    const int l = tid & 63, wv = tid >> 6;
    const int bid = blockIdx.x;
    float rmin[4], ra[4];

    if (bid < 512) {                   // dir1
        const int b = bid >> 6, sub = bid & 63;
        cd_scan2<6>(shape + ((size_t)b * SHAPE_N + sub * 128) * 6,
                    (const uint4*)(ws + SKC_OFF) + (size_t)b * 4096,
                    sB, rmin, ra);
    } else {                           // dir2
        const int j = bid - 512;
        const int b = j >> 6, rem = j & 63;
        const int asub = rem >> 2, bs = rem & 3;
        cd_scan2<3>(skel + ((size_t)b * SKEL_M + asub * 128) * 3,
                    (const uint4*)(ws + SHC_OFF) + (size_t)b * 16384 + bs * 4096,
                    sB, rmin, ra);
    }

    // combine the 4 waves' partial mins (each saw 1/4 of the b-points)
    if (l < 32) {
#pragma unroll
        for (int j = 0; j < 4; ++j) smin[wv][j * 32 + l] = rmin[j];
        if (wv == 0) {
#pragma unroll
            for (int j = 0; j < 4; ++j) sra[j * 32 + l] = ra[j];
        }
    }
    __syncthreads();

    if (bid < 512) {
        float d = 0.f;
        if (tid < 128) {
            const float m = fminf(fminf(smin[0][tid], smin[1][tid]),
                                  fminf(smin[2][tid], smin[3][tid]));
            d = sqrtf(fmaxf(sra[tid] + m, 0.f));
        }
        for (int o = 32; o; o >>= 1) d += __shfl_down(d, o, 64);
        if (l == 0 && wv < 2) s_wsum[wv] = d;
        __syncthreads();
        if (tid == 0) ws[bid] = s_wsum[0] + s_wsum[1];
    } else {
        if (tid < 128) {
            const int j = bid - 512;
            const int b = j >> 6, rem = j & 63;
            const int asub = rem >> 2, bs = rem & 3;
            const float m = fminf(fminf(smin[0][tid], smin[1][tid]),
                                  fminf(smin[2][tid], smin[3][tid]));
            ws[WS2_OFF + bs * (BATCH * SKEL_M) + b * SKEL_M +
               asub * 128 + tid] = sra[tid] + m;
        }
    }
}

// ---------------------------------------------------------------------------
// Single-block reduce (no atomics, no pre-zeroed out): min-fold the 4 dir2
// quarters (float4 loads over 256 KB, L2-resident), clamp+sqrt+sum, add the
// 512 dir1 partials, write out[0].
// ---------------------------------------------------------------------------
__global__ __launch_bounds__(1024) void cd_reduce(
    const float* __restrict__ ws, float* __restrict__ out)
{
    __shared__ float s_wsum[16];
    const int t = threadIdx.x;
    float s = 0.f;

    const float4* w4 = (const float4*)(ws + WS2_OFF);
#pragma unroll
    for (int r = 0; r < 4; ++r) {
        const int i4 = r * 1024 + t;          // float4 index within 4096
        float4 v0 = w4[i4];
        const float4 v1 = w4[4096 + i4];
        const float4 v2 = w4[8192 + i4];
        const float4 v3 = w4[12288 + i4];
        v0.x = fminf(fminf(v0.x, v1.x), fminf(v2.x, v3.x));
        v0.y = fminf(fminf(v0.y, v1.y), fminf(v2.y, v3.y));
        v0.z = fminf(fminf(v0.z, v1.z), fminf(v2.z, v3.z));
        v0.w = fminf(fminf(v0.w, v1.w), fminf(v2.w, v3.w));
        s += sqrtf(fmaxf(v0.x, 0.f)) + sqrtf(fmaxf(v0.y, 0.f)) +
             sqrtf(fmaxf(v0.z, 0.f)) + sqrtf(fmaxf(v0.w, 0.f));
    }
    if (t < 512) s += ws[t];                  // dir1 per-block partial sums

    for (int o = 32; o; o >>= 1) s += __shfl_down(s, o, 64);
    const int lane = t & 63, wave = t >> 6;
    if (lane == 0) s_wsum[wave] = s;
    __syncthreads();
    if (t == 0) {
        float tot = 0.f;
#pragma unroll
        for (int w = 0; w < 16; ++w) tot += s_wsum[w];
        out[0] = tot * 1e-4f;
    }
}

extern "C" void kernel_launch(void* const* d_in, const int* in_sizes, int n_in,
                              void* d_out, int out_size, void* d_ws, size_t ws_size,
                              hipStream_t stream) {
    const float* shape = (const float*)d_in[0];   // (8, 8192, 6) — use first 3
    const float* skel  = (const float*)d_in[1];   // (8, 2048, 3)
    float* out         = (float*)d_out;           // scalar
    float* ws          = (float*)d_ws;            // >= 721408 floats = 2.82 MB

    cd_prep<<<320, 256, 0, stream>>>(shape, skel, ws);
    cd_main<<<1024, 256, 0, stream>>>(shape, skel, ws);
    cd_reduce<<<1, 1024, 0, stream>>>(ws, out);
}